// Round 3
// baseline (99.257 us; speedup 1.0000x reference)
//
#include <hip/hip_runtime.h>

#define SPAN_W 32

// Fused: per-span logit dots + exact reference masked-softmax + weighted
// gather, one block (192 threads = 3 waves) per span. seq rows are read
// twice (dot pass + gather pass) but are L2/L3-resident (25 MB total).
// Assumes D == 768 (192 float4), as fixed by the reference setup.
__global__ __launch_bounds__(192) void fused_span_kernel(
    const float* __restrict__ seq,     // (B,T,D)
    const int*   __restrict__ spans,   // (B,N,2)
    const float* __restrict__ att_w,   // (D,1)
    const float* __restrict__ att_b,   // (1,)
    float*       __restrict__ out,     // (B,N,D)
    int T, int D, int N)
{
    int span = blockIdx.x;             // b*N + n
    int b    = span / N;

    int s0 = spans[(size_t)span * 2 + 0];
    int e0 = spans[(size_t)span * 2 + 1];   // inclusive end
    int width = e0 - s0;

    int tid  = threadIdx.x;
    int wave = tid >> 6;               // 0..2
    int lane = tid & 63;

    __shared__ float zbuf[SPAN_W];
    __shared__ float att[SPAN_W];

    const float*  base = seq + (size_t)b * T * D;
    const float4* w4   = reinterpret_cast<const float4*>(att_w);

    // att_w slice cached in registers, reused across ~11 rows per wave.
    float4 wa = w4[lane];
    float4 wb = w4[lane + 64];
    float4 wc = w4[lane + 128];
    float  bias = att_b[0];

    // Pass 1: logit dot for each (valid) span row; rows strided over waves.
    // Masked rows get z = 0 exactly (reference: softmax(logits * mask)).
    for (int r = wave; r < SPAN_W; r += 3) {
        int  raw = e0 - r;
        bool m   = (r <= width) && (raw >= 0);   // wave-uniform
        float z  = 0.f;
        if (m) {
            const float4* p =
                reinterpret_cast<const float4*>(base + (size_t)raw * D);
            float4 v0 = p[lane], v1 = p[lane + 64], v2 = p[lane + 128];
            z = v0.x*wa.x + v0.y*wa.y + v0.z*wa.z + v0.w*wa.w
              + v1.x*wb.x + v1.y*wb.y + v1.z*wb.z + v1.w*wb.w
              + v2.x*wc.x + v2.y*wc.y + v2.z*wc.z + v2.w*wc.w;
        }
        #pragma unroll
        for (int off = 32; off > 0; off >>= 1)
            z += __shfl_xor(z, off);
        if (lane == 0)
            zbuf[r] = m ? (z + bias) : 0.f;
    }
    __syncthreads();

    // Pass 2: masked softmax over the 32 slots (lanes 0..31 of wave 0),
    // replicating the reference term-for-term.
    if (tid < SPAN_W) {
        int r   = tid;
        float z = zbuf[r];
        float zmax = z;
        #pragma unroll
        for (int off = 16; off > 0; off >>= 1)
            zmax = fmaxf(zmax, __shfl_xor(zmax, off));
        float e = __expf(z - zmax);
        float S = e;
        #pragma unroll
        for (int off = 16; off > 0; off >>= 1)
            S += __shfl_xor(S, off);
        bool  m = (r <= width) && (e0 - r >= 0);
        float t = m ? (e / S) : 0.0f;     // softmax * mask
        float Tt = t;
        #pragma unroll
        for (int off = 16; off > 0; off >>= 1)
            Tt += __shfl_xor(Tt, off);
        att[r] = t / (Tt + 1e-13f);       // exactly 0 when masked
    }
    __syncthreads();

    // Pass 3: weighted sum, 8 independent float4 loads in flight.
    int nvalid = width + 1;
    if (nvalid > SPAN_W) nvalid = SPAN_W;
    if (nvalid < 1) nvalid = 1;

    float4 acc = make_float4(0.f, 0.f, 0.f, 0.f);
    for (int w0 = 0; w0 < nvalid; w0 += 8) {
        float4 v[8];
        float  a[8];
        #pragma unroll
        for (int i = 0; i < 8; ++i) {
            int w   = w0 + i;                  // <= 31 (w0 <= 24)
            int idx = e0 - w; if (idx < 0) idx = 0;
            a[i] = att[w];                     // 0 beyond nvalid
            v[i] = reinterpret_cast<const float4*>(base + (size_t)idx * D)[tid];
        }
        #pragma unroll
        for (int i = 0; i < 8; ++i) {
            acc.x += a[i] * v[i].x;
            acc.y += a[i] * v[i].y;
            acc.z += a[i] * v[i].z;
            acc.w += a[i] * v[i].w;
        }
    }
    reinterpret_cast<float4*>(out + (size_t)span * D)[tid] = acc;
}

extern "C" void kernel_launch(void* const* d_in, const int* in_sizes, int n_in,
                              void* d_out, int out_size, void* d_ws, size_t ws_size,
                              hipStream_t stream)
{
    const float* seq   = (const float*)d_in[0];
    const int*   spans = (const int*)  d_in[1];
    const float* att_w = (const float*)d_in[2];
    const float* att_b = (const float*)d_in[3];
    float*       out   = (float*)d_out;

    const int D  = in_sizes[2];            // 768 (att_w is D x 1)
    const int B  = 4;                      // fixed per reference setup_inputs
    const int BT = in_sizes[0] / D;        // 8192
    const int T  = BT / B;                 // 2048
    const int BN = out_size / D;           // 2048
    const int N  = BN / B;                 // 512

    fused_span_kernel<<<BN, 192, 0, stream>>>(seq, spans, att_w, att_b, out, T, D, N);
}